// Round 3
// baseline (282.826 us; speedup 1.0000x reference)
//
#include <hip/hip_runtime.h>

// ---------------------------------------------------------------------------
// Stage sizes (floats)
//   x:       [32, 3, 128, 128]
//   y  (ws): [32, 32, 64, 64]   = 4,194,304   (conv+relu+pool out)
//   g  (ws): [32, 4096, 64]     = 8,388,608   (GCN out = "flat")
//   part(ws):[1024, 4096]       = 4,194,304   (fc1 split-K partials)
//   f1 (ws): [32, 128]          = 4,096
//   out:     [32, 101]
// ---------------------------------------------------------------------------

#define K_FC 262144

// ========================= Kernel 1: conv+relu+pool =========================
__global__ __launch_bounds__(256) void k_conv_pool(
    const float* __restrict__ x, const float* __restrict__ cw,
    const float* __restrict__ cb, float* __restrict__ y)
{
    __shared__ float wl[864];            // 32*3*3*3 weights
    __shared__ float tin[3 * 34 * 36];   // 34x34 input patch per channel, row pad->36

    int blk = blockIdx.x;
    int b = blk >> 4;
    int tile = blk & 15;
    int ph0 = (tile >> 2) << 4;
    int pw0 = (tile & 3) << 4;
    int t = threadIdx.x;

    for (int i = t; i < 864; i += 256) wl[i] = cw[i];

    int r0 = ph0 * 2 - 1;
    int c0 = pw0 * 2 - 1;
    for (int i = t; i < 3 * 34 * 34; i += 256) {
        int ci = i / 1156;
        int rem = i - ci * 1156;
        int yy = rem / 34;
        int xx = rem - yy * 34;
        int gr = r0 + yy, gc = c0 + xx;
        float v = 0.f;
        if (gr >= 0 && gr < 128 && gc >= 0 && gc < 128)
            v = x[((b * 3 + ci) * 128 + gr) * 128 + gc];
        tin[ci * 1224 + yy * 36 + xx] = v;
    }
    __syncthreads();

    int ph = t >> 4, pw = t & 15;
    float p[3][4][4];
#pragma unroll
    for (int ci = 0; ci < 3; ++ci)
#pragma unroll
        for (int dy = 0; dy < 4; ++dy) {
            const float2* row = (const float2*)&tin[ci * 1224 + (2 * ph + dy) * 36 + 2 * pw];
            float2 v0 = row[0], v1 = row[1];
            p[ci][dy][0] = v0.x; p[ci][dy][1] = v0.y;
            p[ci][dy][2] = v1.x; p[ci][dy][3] = v1.y;
        }

    int obase = (b * 32 * 64 + (ph0 + ph)) * 64 + pw0 + pw;
    for (int co = 0; co < 32; ++co) {
        float s00 = 0.f, s01 = 0.f, s10 = 0.f, s11 = 0.f;
#pragma unroll
        for (int ci = 0; ci < 3; ++ci)
#pragma unroll
            for (int ky = 0; ky < 3; ++ky)
#pragma unroll
                for (int kx = 0; kx < 3; ++kx) {
                    float wv = wl[co * 27 + ci * 9 + ky * 3 + kx];
                    s00 = fmaf(p[ci][ky][kx],         wv, s00);
                    s01 = fmaf(p[ci][ky][kx + 1],     wv, s01);
                    s10 = fmaf(p[ci][ky + 1][kx],     wv, s10);
                    s11 = fmaf(p[ci][ky + 1][kx + 1], wv, s11);
                }
        float m = fmaxf(fmaxf(s00, s01), fmaxf(s10, s11)) + cb[co];
        y[obase + co * 4096] = fmaxf(m, 0.f);
    }
}

// ============================ Kernel 2: GCN =================================
// z stored TRANSPOSED [k][node] so phase-2 reads are per-lane distinct b128s.
__device__ __forceinline__ float dinvf(int h, int w) {
    int d = 1 + (w > 0) + (w < 63) + (h > 0) + (h < 63);
    return rsqrtf((float)d);
}

__device__ __forceinline__ void acc4(const float* __restrict__ yb, int hq, int wq,
                                     int fh, float c,
                                     float4& a0, float4& a1, float4& a2, float4& a3)
{
    const float4* s = (const float4*)(yb + (((hq << 6) + wq) << 5) + fh);
    float4 v0 = s[0], v1 = s[1], v2 = s[2], v3 = s[3];
    a0.x = fmaf(c, v0.x, a0.x); a0.y = fmaf(c, v0.y, a0.y);
    a0.z = fmaf(c, v0.z, a0.z); a0.w = fmaf(c, v0.w, a0.w);
    a1.x = fmaf(c, v1.x, a1.x); a1.y = fmaf(c, v1.y, a1.y);
    a1.z = fmaf(c, v1.z, a1.z); a1.w = fmaf(c, v1.w, a1.w);
    a2.x = fmaf(c, v2.x, a2.x); a2.y = fmaf(c, v2.y, a2.y);
    a2.z = fmaf(c, v2.z, a2.z); a2.w = fmaf(c, v2.w, a2.w);
    a3.x = fmaf(c, v3.x, a3.x); a3.y = fmaf(c, v3.y, a3.y);
    a3.z = fmaf(c, v3.z, a3.z); a3.w = fmaf(c, v3.w, a3.w);
}

__global__ __launch_bounds__(256) void k_gcn(
    const float* __restrict__ y, const float* __restrict__ gw,
    const float* __restrict__ gb, float* __restrict__ g)
{
    __shared__ float zl[32 * 132];    // [k][node 0..127], pitch 132
    __shared__ float wl[32 * 64];     // [k][f] (gw is [32][64] row-major already)
    __shared__ float bl[64];

    int blk = blockIdx.x;
    int b = blk >> 5;
    int r = blk & 31;                 // grid rows 2r, 2r+1
    int t = threadIdx.x;
    const float* yb = y + b * 131072;

    for (int i = t; i < 512; i += 256) ((float4*)wl)[i] = ((const float4*)gw)[i];
    if (t < 64) bl[t] = gb[t];

    // ---- phase 1: aggregate raw 32-dim feats, store transposed
    {
        int l = t >> 1;               // local node 0..127
        int fh = (t & 1) << 4;        // feature half
        int h = 2 * r + (l >> 6);
        int wq = l & 63;
        float dp = dinvf(h, wq);
        float4 a0 = {0,0,0,0}, a1 = {0,0,0,0}, a2 = {0,0,0,0}, a3 = {0,0,0,0};
        acc4(yb, h, wq, fh, dp * dp, a0, a1, a2, a3);
        if (wq > 0)  acc4(yb, h, wq - 1, fh, dp * dinvf(h, wq - 1), a0, a1, a2, a3);
        if (wq < 63) acc4(yb, h, wq + 1, fh, dp * dinvf(h, wq + 1), a0, a1, a2, a3);
        if (h > 0)   acc4(yb, h - 1, wq, fh, dp * dinvf(h - 1, wq), a0, a1, a2, a3);
        if (h < 63)  acc4(yb, h + 1, wq, fh, dp * dinvf(h + 1, wq), a0, a1, a2, a3);
        zl[(fh + 0)  * 132 + l] = a0.x; zl[(fh + 1)  * 132 + l] = a0.y;
        zl[(fh + 2)  * 132 + l] = a0.z; zl[(fh + 3)  * 132 + l] = a0.w;
        zl[(fh + 4)  * 132 + l] = a1.x; zl[(fh + 5)  * 132 + l] = a1.y;
        zl[(fh + 6)  * 132 + l] = a1.z; zl[(fh + 7)  * 132 + l] = a1.w;
        zl[(fh + 8)  * 132 + l] = a2.x; zl[(fh + 9)  * 132 + l] = a2.y;
        zl[(fh + 10) * 132 + l] = a2.z; zl[(fh + 11) * 132 + l] = a2.w;
        zl[(fh + 12) * 132 + l] = a3.x; zl[(fh + 13) * 132 + l] = a3.y;
        zl[(fh + 14) * 132 + l] = a3.z; zl[(fh + 15) * 132 + l] = a3.w;
    }
    __syncthreads();

    // ---- phase 2: [128 n x 32 k] x [32 k x 64 f], thread tile 4n x 8f
    int fg = t & 7;
    int ng = t >> 3;                  // 0..31
    int n0 = ng << 2;
    int f0 = fg << 3;

    float acc[4][8];
#pragma unroll
    for (int i = 0; i < 4; ++i)
#pragma unroll
        for (int jj = 0; jj < 8; ++jj) acc[i][jj] = 0.f;

#pragma unroll 8
    for (int k = 0; k < 32; ++k) {
        float4 zv  = *(const float4*)&zl[k * 132 + n0];
        float4 wv0 = *(const float4*)&wl[(k << 6) + f0];
        float4 wv1 = *(const float4*)&wl[(k << 6) + f0 + 4];
        float zs[4] = {zv.x, zv.y, zv.z, zv.w};
        float ws[8] = {wv0.x, wv0.y, wv0.z, wv0.w, wv1.x, wv1.y, wv1.z, wv1.w};
#pragma unroll
        for (int i = 0; i < 4; ++i)
#pragma unroll
            for (int jj = 0; jj < 8; ++jj)
                acc[i][jj] = fmaf(zs[i], ws[jj], acc[i][jj]);
    }

    int pbase = r * 128;
    float* gout = g + (size_t)b * 262144;
#pragma unroll
    for (int i = 0; i < 4; ++i) {
        float4 o0, o1;
        o0.x = fmaxf(acc[i][0] + bl[f0 + 0], 0.f);
        o0.y = fmaxf(acc[i][1] + bl[f0 + 1], 0.f);
        o0.z = fmaxf(acc[i][2] + bl[f0 + 2], 0.f);
        o0.w = fmaxf(acc[i][3] + bl[f0 + 3], 0.f);
        o1.x = fmaxf(acc[i][4] + bl[f0 + 4], 0.f);
        o1.y = fmaxf(acc[i][5] + bl[f0 + 5], 0.f);
        o1.z = fmaxf(acc[i][6] + bl[f0 + 6], 0.f);
        o1.w = fmaxf(acc[i][7] + bl[f0 + 7], 0.f);
        float* op = gout + (size_t)(pbase + n0 + i) * 64 + f0;
        *(float4*)op = o0;
        *(float4*)(op + 4) = o1;
    }
}

// ============================ Kernel 3: fc1 =================================
// Each thread owns ALL 32 batches for 2 j-rows and a k-subrange:
// W goes global->register->FMA exactly once (no LDS, no K-loop barriers).
// A slab (32 x 256) staged once in LDS; reads are 4-addr broadcasts.
// In-block k-split x4 reduced with shfl_xor butterfly over lane&3.
__global__ __launch_bounds__(256, 3) void k_fc1(
    const float* __restrict__ flat, const float* __restrict__ w,
    float* __restrict__ partial)
{
    __shared__ float Al[32 * 264];    // [b][k], pitch 264

    int t = threadIdx.x;
    int blk = blockIdx.x;
    int k0 = blk << 8;

    // stage A slab: 2048 float4, coalesced 1KB rows
#pragma unroll
    for (int rr = 0; rr < 8; ++rr) {
        int idx = (rr << 8) + t;
        int b = idx >> 6;
        int c4 = (idx & 63) << 2;
        *(float4*)&Al[b * 264 + c4] =
            *(const float4*)(flat + (size_t)b * K_FC + k0 + c4);
    }
    __syncthreads();

    int s = t & 3;                    // k-subgroup
    int j2 = t >> 2;                  // 0..63 ; j = j2 and j2+64
    const float* wr0 = w + (size_t)j2 * K_FC + k0 + (s << 2);
    const float* wr1 = wr0 + (size_t)64 * K_FC;

    float acc0[32], acc1[32];
#pragma unroll
    for (int b = 0; b < 32; ++b) { acc0[b] = 0.f; acc1[b] = 0.f; }

#pragma unroll 2
    for (int q = 0; q < 16; ++q) {
        float4 wa = *(const float4*)(wr0 + (q << 4));
        float4 wb = *(const float4*)(wr1 + (q << 4));
        int kk = (q << 4) + (s << 2);
#pragma unroll
        for (int b = 0; b < 32; ++b) {
            float4 a = *(const float4*)&Al[b * 264 + kk];
            acc0[b] = fmaf(a.x, wa.x, acc0[b]);
            acc0[b] = fmaf(a.y, wa.y, acc0[b]);
            acc0[b] = fmaf(a.z, wa.z, acc0[b]);
            acc0[b] = fmaf(a.w, wa.w, acc0[b]);
            acc1[b] = fmaf(a.x, wb.x, acc1[b]);
            acc1[b] = fmaf(a.y, wb.y, acc1[b]);
            acc1[b] = fmaf(a.z, wb.z, acc1[b]);
            acc1[b] = fmaf(a.w, wb.w, acc1[b]);
        }
    }

    // butterfly allreduce over the 4 k-subgroups (lane bits 0..1)
#pragma unroll
    for (int b = 0; b < 32; ++b) {
        acc0[b] += __shfl_xor(acc0[b], 1);
        acc0[b] += __shfl_xor(acc0[b], 2);
        acc1[b] += __shfl_xor(acc1[b], 1);
        acc1[b] += __shfl_xor(acc1[b], 2);
    }

    // each s-lane stores a distinct batch-range
    float* pout = partial + ((size_t)blk << 12);
#pragma unroll
    for (int i = 0; i < 8; ++i) {
        int b = (s << 3) + i;
        pout[b * 128 + j2]      = acc0[b];
        pout[b * 128 + j2 + 64] = acc1[b];
    }
}

// ==================== Kernel 3b: split-K partial reduce =====================
__global__ __launch_bounds__(256) void k_red(
    const float* __restrict__ partial, float* __restrict__ f1)
{
    __shared__ float4 Sl[256];
    int t = threadIdx.x;
    int e4 = (blockIdx.x << 2) + (t & 3);
    int ng = t >> 2;
    const float4* p = (const float4*)partial;
    float4 a = {0.f, 0.f, 0.f, 0.f};
#pragma unroll
    for (int i = 0; i < 16; ++i) {
        int ns = ng + (i << 6);
        float4 v = p[(size_t)ns * 1024 + e4];
        a.x += v.x; a.y += v.y; a.z += v.z; a.w += v.w;
    }
    Sl[t] = a;
    __syncthreads();
    for (int off = 128; off >= 4; off >>= 1) {
        if (t < off) {
            float4 u = Sl[t], v = Sl[t + off];
            u.x += v.x; u.y += v.y; u.z += v.z; u.w += v.w;
            Sl[t] = u;
        }
        __syncthreads();
    }
    if (t < 4) ((float4*)f1)[(blockIdx.x << 2) + t] = Sl[t];
}

// ============================ Kernel 4: fc2 =================================
__global__ __launch_bounds__(256) void k_fc2(
    const float* __restrict__ f1, const float* __restrict__ b1,
    const float* __restrict__ w2, const float* __restrict__ b2,
    float* __restrict__ out)
{
    int idx = blockIdx.x * 256 + threadIdx.x;
    if (idx >= 32 * 101) return;
    int b = idx / 101;
    int c = idx - b * 101;
    const float4* fp = (const float4*)(f1 + b * 128);
    const float4* bp = (const float4*)b1;
    const float4* wp = (const float4*)(w2 + c * 128);
    float acc = b2[c];
#pragma unroll
    for (int q = 0; q < 32; ++q) {
        float4 f = fp[q], bb = bp[q], ww = wp[q];
        acc = fmaf(fmaxf(f.x + bb.x, 0.f), ww.x, acc);
        acc = fmaf(fmaxf(f.y + bb.y, 0.f), ww.y, acc);
        acc = fmaf(fmaxf(f.z + bb.z, 0.f), ww.z, acc);
        acc = fmaf(fmaxf(f.w + bb.w, 0.f), ww.w, acc);
    }
    out[idx] = acc;
}

// ================================ launch ====================================
extern "C" void kernel_launch(void* const* d_in, const int* in_sizes, int n_in,
                              void* d_out, int out_size, void* d_ws, size_t ws_size,
                              hipStream_t stream)
{
    const float* x  = (const float*)d_in[0];
    const float* cw = (const float*)d_in[1];
    const float* cb = (const float*)d_in[2];
    const float* gw = (const float*)d_in[3];
    const float* gb = (const float*)d_in[4];
    const float* w1 = (const float*)d_in[5];
    const float* b1 = (const float*)d_in[6];
    const float* w2 = (const float*)d_in[7];
    const float* b2 = (const float*)d_in[8];
    float* out = (float*)d_out;

    float* y       = (float*)d_ws;           // 4,194,304
    float* g       = y + 4194304;            // 8,388,608
    float* partial = g + 8388608;            // 4,194,304
    float* f1      = partial + 4194304;      // 4,096

    k_conv_pool<<<512, 256, 0, stream>>>(x, cw, cb, y);
    k_gcn<<<1024, 256, 0, stream>>>(y, gw, gb, g);
    k_fc1<<<1024, 256, 0, stream>>>(g, w1, partial);
    k_red<<<256, 256, 0, stream>>>(partial, f1);
    k_fc2<<<13, 256, 0, stream>>>(f1, b1, w2, b2, out);
}